// Round 3
// baseline (5239.101 us; speedup 1.0000x reference)
//
#include <hip/hip_runtime.h>
#include <math.h>

// DecoderLSTM greedy decode, MI355X. V=32000 H=1024 T=32 B=64.
// Logits GEMM: bf16 MFMA (16x16x32) with 3-term split (hi*hi + hi*lo + lo*hi),
// fp32 accumulate. Gates GEMM fp32 (recurrence amplifies error).
//
// R3 == R2 resubmit (container failed twice on infra; kernel audited clean:
// no spin-waits, 16B-aligned vector accesses, LDS 42.8KB, ws write-before-read).
//  - recur: gates GEMM (full-K, no partials) + LSTM + bf16 h-split fused.
//    x never materialized: stages E[amax[b]] rows directly. h stored
//    transposed (hT[b][k]), double-buffered across steps.
//  - logits: MFMA + softmax/argmax partials + last-block finalize
//    (threadfence + atomic counter; finalizing block writes mask/amax).
//
// ws float offsets:
//   c[1024][64]@0  hT0[64][1024]@65536  hT1[64][1024]@131072
//   pmax[250][64]@196608  psum[250][64]@212992  pidx(int)[250][64]@229376
//   counter(int)@245760  amax(int[64])@245824
// ushort (bf16) at float offset 2359296: Whi[32000][1024], Wlo[32000][1024],
//   Hhi[64][1024], Hlo[64][1024]

typedef short bf16x8 __attribute__((ext_vector_type(8)));
typedef float f32x4 __attribute__((ext_vector_type(4)));

constexpr int kH = 1024;
constexpr int kB = 64;
constexpr int kV = 32000;
constexpr int kT = 32;
constexpr int kSOS = 1;
constexpr int kEOS = 2;

__device__ inline unsigned short f2bf(float f) {  // RNE float->bf16
  unsigned int u = __float_as_uint(f);
  u += 0x7fffu + ((u >> 16) & 1u);
  return (unsigned short)(u >> 16);
}
__device__ inline float bf2f(unsigned short h) {
  return __uint_as_float(((unsigned int)h) << 16);
}

// ---------------------------------------------------------------- init ------
__global__ __launch_bounds__(256) void init_kernel(
    const float* __restrict__ eh, const float* __restrict__ ec,
    float* __restrict__ ws) {
  int g = blockIdx.x * 256 + threadIdx.x;  // grid 512 -> 0..131071
  float* c = ws;
  float* hT0 = ws + 65536;
  int* counter = (int*)(ws + 245760);
  int* amax = (int*)(ws + 245824);
  if (g < 65536) {
    int u = g >> 6, b = g & 63;
    c[u * 64 + b] = ec[(size_t)b * kH + u];
  } else {
    int i = g - 65536;
    hT0[i] = eh[i];  // eh is [b][u] row-major == hT layout
  }
  if (g < 64) amax[g] = kSOS;
  if (g == 64) *counter = 0;
}

// ------------------------------------------------------------- W split ------
__global__ __launch_bounds__(256) void wsplit_kernel(
    const float* __restrict__ W, unsigned short* __restrict__ hi,
    unsigned short* __restrict__ lo) {
  size_t i = ((size_t)blockIdx.x * 256 + threadIdx.x) * 4;
  float4 w = *(const float4*)(W + i);
  unsigned short h0 = f2bf(w.x), h1 = f2bf(w.y), h2 = f2bf(w.z), h3 = f2bf(w.w);
  ushort4 hv = make_ushort4(h0, h1, h2, h3);
  ushort4 lv = make_ushort4(f2bf(w.x - bf2f(h0)), f2bf(w.y - bf2f(h1)),
                            f2bf(w.z - bf2f(h2)), f2bf(w.w - bf2f(h3)));
  *(ushort4*)(hi + i) = hv;
  *(ushort4*)(lo + i) = lv;
}

// --------------------------------------------------- recur (gates+lstm) -----
// 256 blocks x 256 thr. Block owns u0..u0+3. Thread (rg=wave, b=lane) owns
// the 4 gates of u = u0+rg for batch b. Full-K GEMM over 2 phases:
//   phase 0: z rows = E[amax[b]]  (x gather fused)
//   phase 1: z rows = hTprev[b]
// K chunks of 128, register-prefetch double buffer; W reads broadcast in
// wave; Zt stride 132 floats -> b128 reads, 16B-aligned rows.
__global__ __launch_bounds__(256) void recur_kernel(
    const float* __restrict__ Wih, const float* __restrict__ Whh,
    const float* __restrict__ E, const float* __restrict__ bih,
    const float* __restrict__ bhh, const int* __restrict__ amax,
    const float* __restrict__ hTprev, float* __restrict__ hTnext,
    float* __restrict__ c, unsigned short* __restrict__ Hhi,
    unsigned short* __restrict__ Hlo) {
  __shared__ __align__(16) float Wt[16 * 132];
  __shared__ __align__(16) float Zt[64 * 132];
  __shared__ const float* rowp[64];
  const int tid = threadIdx.x;
  const int u0 = blockIdx.x * 4;
  const int rg = tid >> 6;  // wave index = u offset
  const int b = tid & 63;

  if (tid < 64) rowp[tid] = E + (size_t)amax[tid] * kH;
  __syncthreads();

  f32x4 acc[4];
#pragma unroll
  for (int j = 0; j < 4; ++j) acc[j] = (f32x4){0.f, 0.f, 0.f, 0.f};

  f32x4 wreg[2], zreg[8];
  auto prefetch = [&](int cidx) {
    const int ph = cidx >> 3;
    const int kc = (cidx & 7) * 128;
    const float* __restrict__ Wb = ph ? Whh : Wih;
#pragma unroll
    for (int l = 0; l < 2; ++l) {
      int s = tid + 256 * l, ri = s >> 5, kq = s & 31;
      size_t grow = (size_t)((ri >> 2) * kH + u0 + (ri & 3));
      wreg[l] = *(const f32x4*)(Wb + grow * kH + kc + kq * 4);
    }
#pragma unroll
    for (int l = 0; l < 8; ++l) {
      int s = tid + 256 * l, zb = s >> 5, kq = s & 31;
      const float* zp = ph ? (hTprev + (size_t)zb * kH) : rowp[zb];
      zreg[l] = *(const f32x4*)(zp + kc + kq * 4);
    }
  };

  prefetch(0);
  for (int cidx = 0; cidx < 16; ++cidx) {
    // regs -> LDS
#pragma unroll
    for (int l = 0; l < 2; ++l) {
      int s = tid + 256 * l;
      *(f32x4*)(&Wt[(s >> 5) * 132 + (s & 31) * 4]) = wreg[l];
    }
#pragma unroll
    for (int l = 0; l < 8; ++l) {
      int s = tid + 256 * l;
      *(f32x4*)(&Zt[(s >> 5) * 132 + (s & 31) * 4]) = zreg[l];
    }
    __syncthreads();
    if (cidx < 15) prefetch(cidx + 1);  // latency hides under compute
    const float* ztb = Zt + b * 132;
    const float* wtb = Wt + rg * 132;
#pragma unroll
    for (int k4 = 0; k4 < 32; ++k4) {
      f32x4 z4 = *(const f32x4*)(ztb + k4 * 4);
      acc[0] += (*(const f32x4*)(wtb + k4 * 4)) * z4;
      acc[1] += (*(const f32x4*)(wtb + 528 + k4 * 4)) * z4;
      acc[2] += (*(const f32x4*)(wtb + 1056 + k4 * 4)) * z4;
      acc[3] += (*(const f32x4*)(wtb + 1584 + k4 * 4)) * z4;
    }
    __syncthreads();
  }

  // LSTM epilogue: thread has all 4 gates of (u, b).
  const int u = u0 + rg;
  float gate[4];
#pragma unroll
  for (int j = 0; j < 4; ++j)
    gate[j] = acc[j][0] + acc[j][1] + acc[j][2] + acc[j][3] + bih[j * kH + u] +
              bhh[j * kH + u];
  float gi = 1.f / (1.f + expf(-gate[0]));
  float gf = 1.f / (1.f + expf(-gate[1]));
  float gg = tanhf(gate[2]);
  float go = 1.f / (1.f + expf(-gate[3]));
  float cn = gf * c[u * 64 + b] + gi * gg;
  float hn = go * tanhf(cn);
  c[u * 64 + b] = cn;
  hTnext[(size_t)b * kH + u] = hn;
  unsigned short hb = f2bf(hn);
  Hhi[(size_t)b * kH + u] = hb;
  Hlo[(size_t)b * kH + u] = f2bf(hn - bf2f(hb));
}

// ------------------------------------------------------- logits (MFMA) ------
struct Frags {
  bf16x8 ah[2], al[2], bh[4], bl[4];
};

__device__ inline void load_frags(Frags& f, const unsigned short* wp0,
                                  const unsigned short* wp1,
                                  const unsigned short* lp0,
                                  const unsigned short* lp1,
                                  const unsigned short* hh,
                                  const unsigned short* hl, int ko) {
  f.ah[0] = *(const bf16x8*)(wp0 + ko);
  f.ah[1] = *(const bf16x8*)(wp1 + ko);
  f.al[0] = *(const bf16x8*)(lp0 + ko);
  f.al[1] = *(const bf16x8*)(lp1 + ko);
#pragma unroll
  for (int bt = 0; bt < 4; ++bt) {
    f.bh[bt] = *(const bf16x8*)(hh + bt * 16 * kH + ko);
    f.bl[bt] = *(const bf16x8*)(hl + bt * 16 * kH + ko);
  }
}

__device__ inline void do_mfma(const Frags& f, f32x4 acc[2][4]) {
#pragma unroll
  for (int tv = 0; tv < 2; ++tv)
#pragma unroll
    for (int bt = 0; bt < 4; ++bt) {
      acc[tv][bt] = __builtin_amdgcn_mfma_f32_16x16x32_bf16(
          f.ah[tv], f.bh[bt], acc[tv][bt], 0, 0, 0);
      acc[tv][bt] = __builtin_amdgcn_mfma_f32_16x16x32_bf16(
          f.ah[tv], f.bl[bt], acc[tv][bt], 0, 0, 0);
      acc[tv][bt] = __builtin_amdgcn_mfma_f32_16x16x32_bf16(
          f.al[tv], f.bh[bt], acc[tv][bt], 0, 0, 0);
    }
}

__global__ __launch_bounds__(256) void logits_mfma_kernel(
    const unsigned short* __restrict__ Whi, const unsigned short* __restrict__ Wlo,
    const unsigned short* __restrict__ Hhi, const unsigned short* __restrict__ Hlo,
    const float* __restrict__ bout, float* __restrict__ out,
    float* __restrict__ pmax_g, float* __restrict__ psum_g,
    int* __restrict__ pidx_g, int* __restrict__ counter,
    int* __restrict__ amax_out, float* __restrict__ mask) {
  const int tid = threadIdx.x;
  const int wave = tid >> 6, lane = tid & 63;
  const int m = lane & 15, q = lane >> 4;
  const int v0 = blockIdx.x * 128 + wave * 32;
  const unsigned short* wp0 = Whi + (size_t)(v0 + m) * kH + q * 8;
  const unsigned short* wp1 = Whi + (size_t)(v0 + 16 + m) * kH + q * 8;
  const unsigned short* lp0 = Wlo + (size_t)(v0 + m) * kH + q * 8;
  const unsigned short* lp1 = Wlo + (size_t)(v0 + 16 + m) * kH + q * 8;
  const unsigned short* hh = Hhi + (size_t)m * kH + q * 8;
  const unsigned short* hl = Hlo + (size_t)m * kH + q * 8;

  f32x4 acc[2][4];
#pragma unroll
  for (int tv = 0; tv < 2; ++tv)
#pragma unroll
    for (int bt = 0; bt < 4; ++bt) acc[tv][bt] = (f32x4){0.f, 0.f, 0.f, 0.f};

  Frags f0, f1;
  load_frags(f0, wp0, wp1, lp0, lp1, hh, hl, 0);
  for (int kc = 0; kc < kH; kc += 64) {
    if (kc + 32 < kH) load_frags(f1, wp0, wp1, lp0, lp1, hh, hl, kc + 32);
    do_mfma(f0, acc);
    if (kc + 64 < kH) load_frags(f0, wp0, wp1, lp0, lp1, hh, hl, kc + 64);
    do_mfma(f1, acc);
  }

  // bias in-place; store logits. D layout: row(v)=q*4+reg, col(b)=lane&15.
  float4 bo0 = *(const float4*)(bout + v0 + q * 4);
  float4 bo1 = *(const float4*)(bout + v0 + 16 + q * 4);
#pragma unroll
  for (int tv = 0; tv < 2; ++tv) {
    float4 bo = tv ? bo1 : bo0;
#pragma unroll
    for (int bt = 0; bt < 4; ++bt) {
      int b = bt * 16 + m;
      f32x4 a = acc[tv][bt];
      a[0] += bo.x; a[1] += bo.y; a[2] += bo.z; a[3] += bo.w;
      acc[tv][bt] = a;
      float4 o = make_float4(a[0], a[1], a[2], a[3]);
      *(float4*)(out + (size_t)b * kV + v0 + tv * 16 + q * 4) = o;
    }
  }

  // ---- per-block softmax/argmax partials, layout [blk][64] (coalesced)
  __shared__ float lred[4][4][64];
  __shared__ int lidx[4][4][64];
  __shared__ float bbm[64];
  const int blk = blockIdx.x;
  const int vbase = blk * 128;

#pragma unroll
  for (int bt = 0; bt < 4; ++bt) {
    float pmv = -INFINITY;
    int piv = 0x7fffffff;
#pragma unroll
    for (int tv = 0; tv < 2; ++tv)
#pragma unroll
      for (int r = 0; r < 4; ++r) {
        float val = acc[tv][bt][r];
        int v = vbase + wave * 32 + tv * 16 + q * 4 + r;
        if (val > pmv) { pmv = val; piv = v; }
      }
    lred[wave][q][bt * 16 + m] = pmv;
    lidx[wave][q][bt * 16 + m] = piv;
  }
  __syncthreads();
  if (tid < 64) {
    float bm = -INFINITY;
    int bi = 0x7fffffff;
#pragma unroll
    for (int w = 0; w < 4; ++w)
#pragma unroll
      for (int qq = 0; qq < 4; ++qq) {
        float v2 = lred[w][qq][tid];
        int i2 = lidx[w][qq][tid];
        if (v2 > bm || (v2 == bm && i2 < bi)) { bm = v2; bi = i2; }
      }
    bbm[tid] = bm;
    pmax_g[(size_t)blk * 64 + tid] = bm;
    pidx_g[(size_t)blk * 64 + tid] = bi;
  }
  __syncthreads();
#pragma unroll
  for (int bt = 0; bt < 4; ++bt) {
    float bm = bbm[bt * 16 + m];
    float s = 0.f;
#pragma unroll
    for (int tv = 0; tv < 2; ++tv)
#pragma unroll
      for (int r = 0; r < 4; ++r) s += expf(acc[tv][bt][r] - bm);
    lred[wave][q][bt * 16 + m] = s;
  }
  __syncthreads();
  if (tid < 64) {
    float s = 0.f;
#pragma unroll
    for (int w = 0; w < 4; ++w)
#pragma unroll
      for (int qq = 0; qq < 4; ++qq) s += lred[w][qq][tid];
    psum_g[(size_t)blk * 64 + tid] = s;
  }

  // ---- last-block finalize (threadfence reduction pattern, no spin)
  __shared__ int is_last;
  __threadfence();
  __syncthreads();
  if (tid == 0) is_last = (atomicAdd(counter, 1) == 249);
  __syncthreads();
  if (!is_last) return;
  __threadfence();

  __shared__ float fm[4][64];
  __shared__ int fi[4][64];
  __shared__ float fs[4][64];
  const int qq = tid >> 6, bb = tid & 63;
  float mx = -INFINITY;
  int idx = 0x7fffffff;
  for (int k = qq; k < 250; k += 4) {
    float v = pmax_g[(size_t)k * 64 + bb];
    int ii = pidx_g[(size_t)k * 64 + bb];
    if (v > mx || (v == mx && ii < idx)) { mx = v; idx = ii; }
  }
  fm[qq][bb] = mx;
  fi[qq][bb] = idx;
  __syncthreads();
  if (tid < 64) {
    float M = fm[0][tid];
    int ai = fi[0][tid];
#pragma unroll
    for (int w = 1; w < 4; ++w) {
      float v = fm[w][tid];
      int ii = fi[w][tid];
      if (v > M || (v == M && ii < ai)) { M = v; ai = ii; }
    }
    fm[0][tid] = M;
    fi[0][tid] = ai;
  }
  __syncthreads();
  float M = fm[0][bb];
  float s = 0.f;
  for (int k = qq; k < 250; k += 4)
    s += psum_g[(size_t)k * 64 + bb] * expf(pmax_g[(size_t)k * 64 + bb] - M);
  fs[qq][bb] = s;
  __syncthreads();
  if (tid < 64) {
    float S = fs[0][tid] + fs[1][tid] + fs[2][tid] + fs[3][tid];
    float eosl = out[(size_t)tid * kV + kEOS];
    mask[tid] = expf(eosl - M) / S;
    amax_out[tid] = fi[0][tid];
    if (tid == 0) *counter = 0;  // reset for next step
  }
}

// -------------------------------------------------------------- launch ------
extern "C" void kernel_launch(void* const* d_in, const int* in_sizes, int n_in,
                              void* d_out, int out_size, void* d_ws,
                              size_t ws_size, hipStream_t stream) {
  const float* E = (const float*)d_in[0];
  const float* Wih = (const float*)d_in[1];
  const float* Whh = (const float*)d_in[2];
  const float* bih = (const float*)d_in[3];
  const float* bhh = (const float*)d_in[4];
  const float* Wout = (const float*)d_in[5];
  const float* bout = (const float*)d_in[6];
  const float* eh = (const float*)d_in[7];
  const float* ec = (const float*)d_in[8];
  float* out = (float*)d_out;
  float* ws = (float*)d_ws;

  float* c = ws;
  float* hT0 = ws + 65536;
  float* hT1 = ws + 131072;
  float* pmaxg = ws + 196608;
  float* psumg = ws + 212992;
  int* pidxg = (int*)(ws + 229376);
  int* counter = (int*)(ws + 245760);
  int* amax = (int*)(ws + 245824);
  unsigned short* Whi = (unsigned short*)(ws + 2359296);
  unsigned short* Wlo = Whi + (size_t)kV * kH;
  unsigned short* Hhi = Wlo + (size_t)kV * kH;
  unsigned short* Hlo = Hhi + (size_t)kB * kH;

  init_kernel<<<512, 256, 0, stream>>>(eh, ec, ws);
  wsplit_kernel<<<kV, 256, 0, stream>>>(Wout, Whi, Wlo);
  for (int t = 0; t < kT; ++t) {
    float* out_t = out + (size_t)t * kB * kV;
    float* hTp = (t & 1) ? hT1 : hT0;
    float* hTn = (t & 1) ? hT0 : hT1;
    recur_kernel<<<256, 256, 0, stream>>>(Wih, Whh, E, bih, bhh, amax, hTp,
                                          hTn, c, Hhi, Hlo);
    logits_mfma_kernel<<<250, 256, 0, stream>>>(
        Whi, Wlo, Hhi, Hlo, bout, out_t, pmaxg, psumg, pidxg, counter, amax,
        out + (size_t)kT * kB * kV + t * kB);
  }
}

// Round 4
// 3390.046 us; speedup vs baseline: 1.5454x; 1.5454x over previous
//
#include <hip/hip_runtime.h>
#include <math.h>

// DecoderLSTM greedy decode, MI355X. V=32000 H=1024 T=32 B=64.
// Logits GEMM: bf16 MFMA (16x16x32) with 3-term split (hi*hi + hi*lo + lo*hi),
// fp32 accumulate. Gates GEMM fp32 (recurrence amplifies error).
//
// R4: revert R3's in-kernel __threadfence finalize (L2 writeback storm on
// non-coherent per-XCD L2s => +71us/step). Back to R1 structure, then:
//  - finalize folded into NEXT step's gates prolog (consumer-side redundant
//    reduction of 250x64 partials -> rowp/mask; coherence via kernel boundary,
//    NO fences). x never materialized; gates stages E[amax[b]] rows directly.
//    4 -> 3 dispatches/step (+1 final_mask after loop).
//  - logits: Hhi/Hlo k-slice staged in LDS per block (16 KB, XOR-granule
//    swizzle; reg-prefetch 1 iter ahead) -> per-wave H re-reads (512 KB/wave
//    from cache) become 1 read/block; per-lane global bytes/iter 384 -> 192.
//    MFMA order unchanged -> bitwise-identical logits (absmax canary).
//
// ws float offsets (x slot @0 unused):
//   h[1024][64]@65536  c[1024][64]@131072
//   pmax[250][64]@196608  psum[250][64]@212992  pidx(int)[250][64]@229376
// ushort (bf16) at float offset 2359296: Whi[32000][1024], Wlo[32000][1024],
//   Hhi[64][1024], Hlo[64][1024]

typedef short bf16x8 __attribute__((ext_vector_type(8)));
typedef unsigned short ush8 __attribute__((ext_vector_type(8)));
typedef float f32x4 __attribute__((ext_vector_type(4)));

constexpr int kH = 1024;
constexpr int kFH = 4096;
constexpr int kB = 64;
constexpr int kV = 32000;
constexpr int kT = 32;
constexpr int kSOS = 1;
constexpr int kEOS = 2;

__device__ inline unsigned short f2bf(float f) {  // RNE float->bf16
  unsigned int u = __float_as_uint(f);
  u += 0x7fffu + ((u >> 16) & 1u);
  return (unsigned short)(u >> 16);
}
__device__ inline float bf2f(unsigned short h) {
  return __uint_as_float(((unsigned int)h) << 16);
}

// ---------------------------------------------------------------- init ------
__global__ __launch_bounds__(256) void init_kernel(
    const float* __restrict__ eh, const float* __restrict__ ec,
    float* __restrict__ ws) {
  int g = blockIdx.x * 256 + threadIdx.x;  // grid 512 -> 0..131071
  float* h = ws + 65536;
  float* c = ws + 131072;
  if (g < 65536) {
    int u = g >> 6, b = g & 63;
    c[u * 64 + b] = ec[(size_t)b * kH + u];
  } else {
    int i = g - 65536;
    int u = i >> 6, b = i & 63;
    h[i] = eh[(size_t)b * kH + u];
  }
}

// ------------------------------------------------------------- W split ------
__global__ __launch_bounds__(256) void wsplit_kernel(
    const float* __restrict__ W, unsigned short* __restrict__ hi,
    unsigned short* __restrict__ lo) {
  size_t i = ((size_t)blockIdx.x * 256 + threadIdx.x) * 4;
  float4 w = *(const float4*)(W + i);
  unsigned short h0 = f2bf(w.x), h1 = f2bf(w.y), h2 = f2bf(w.z), h3 = f2bf(w.w);
  ushort4 hv = make_ushort4(h0, h1, h2, h3);
  ushort4 lv = make_ushort4(f2bf(w.x - bf2f(h0)), f2bf(w.y - bf2f(h1)),
                            f2bf(w.z - bf2f(h2)), f2bf(w.w - bf2f(h3)));
  *(ushort4*)(hi + i) = hv;
  *(ushort4*)(lo + i) = lv;
}

// --------------------------------------------------------------- gates ------
// part[s][r][b] += W[r][k] * z[k][b]. grid(64,8).
// Prolog (phase-0 blocks): reduce prev-step partials -> rowp[b]=&E[amax[b]];
// block (0,0) also writes mask[t-1]. t==0: rowp = &E[SOS]. No fences: the
// partials were written by the previous kernel (boundary = coherence).
__global__ __launch_bounds__(256) void gates_kernel(
    const float* __restrict__ Wih, const float* __restrict__ Whh,
    const float* __restrict__ E, const float* __restrict__ h,
    float* __restrict__ part, const float* __restrict__ pmax_g,
    const float* __restrict__ psum_g, const int* __restrict__ pidx_g,
    const float* __restrict__ out_prev, float* __restrict__ mask_prev, int t) {
  __shared__ __align__(16) float Wt[64 * 68];
  __shared__ __align__(16) float Zt[64 * 68];
  __shared__ const float* rowp[64];
  __shared__ float redA[4][64];
  __shared__ int redI[4][64];
  __shared__ float redS[4][64];
  const int tid = threadIdx.x;
  const int s = blockIdx.y;
  const int r0 = blockIdx.x * 64;
  const int phase = s >> 2;
  const int kc0 = (s & 3) * 256;
  const float* __restrict__ W = phase ? Whh : Wih;

  if (!phase) {
    const int b = tid & 63, kq = tid >> 6;
    if (t == 0) {
      if (tid < 64) rowp[tid] = E + (size_t)kSOS * kH;
    } else {
      float mx = -INFINITY;
      int ix = 0x7fffffff;
      for (int k = kq; k < 250; k += 4) {
        float v = pmax_g[k * 64 + b];
        int ii = pidx_g[k * 64 + b];
        if (v > mx || (v == mx && ii < ix)) { mx = v; ix = ii; }
      }
      redA[kq][b] = mx;
      redI[kq][b] = ix;
      __syncthreads();
      if (tid < 64) {
        float M = redA[0][tid];
        int ai = redI[0][tid];
#pragma unroll
        for (int w2 = 1; w2 < 4; ++w2) {
          float v = redA[w2][tid];
          int ii = redI[w2][tid];
          if (v > M || (v == M && ii < ai)) { M = v; ai = ii; }
        }
        rowp[tid] = E + (size_t)ai * kH;
        redA[0][tid] = M;
      }
      if (blockIdx.x == 0) {  // mask[t-1] (block-uniform branch)
        __syncthreads();
        float M = redA[0][b];
        float sacc = 0.f;
        for (int k = kq; k < 250; k += 4)
          sacc += psum_g[k * 64 + b] * expf(pmax_g[k * 64 + b] - M);
        redS[kq][b] = sacc;
        __syncthreads();
        if (tid < 64) {
          float S = redS[0][tid] + redS[1][tid] + redS[2][tid] + redS[3][tid];
          mask_prev[tid] = expf(out_prev[(size_t)tid * kV + kEOS] - M) / S;
        }
      }
    }
  }
  __syncthreads();

  const int tb4 = tid & 15;
  const int tr4 = tid >> 4;
  float acc[4][4];
#pragma unroll
  for (int i = 0; i < 4; ++i)
#pragma unroll
    for (int j = 0; j < 4; ++j) acc[i][j] = 0.f;

  for (int kc = kc0; kc < kc0 + 256; kc += 64) {
#pragma unroll
    for (int l = 0; l < 4; ++l) {
      int f4 = tid + 256 * l;
      int row = f4 >> 4;
      int c4 = f4 & 15;
      float4 w = *(const float4*)(W + (size_t)(r0 + row) * kH + kc + c4 * 4);
      float wv[4] = {w.x, w.y, w.z, w.w};
#pragma unroll
      for (int cc = 0; cc < 4; ++cc) {
        int c = (cc + c4) & 3;
        Wt[(c4 * 4 + c) * 68 + row] = wv[c];
      }
    }
    if (!phase) {  // z = E[amax[b]] rows (row-major gather, coalesced 1KB/row)
#pragma unroll
      for (int l = 0; l < 4; ++l) {
        int g = tid + 256 * l;  // 0..1023
        int zb = g >> 4, k4 = g & 15;
        f32x4 v = *(const f32x4*)(rowp[zb] + kc + k4 * 4);
#pragma unroll
        for (int j = 0; j < 4; ++j) Zt[(k4 * 4 + j) * 68 + zb] = v[j];
      }
    } else {  // z = h, [k][b] layout (R1 path)
#pragma unroll
      for (int l = 0; l < 4; ++l) {
        int f4 = tid + 256 * l;
        int kk = f4 >> 4;
        int b4 = f4 & 15;
        *(float4*)(&Zt[kk * 68 + b4 * 4]) =
            *(const float4*)(h + (size_t)(kc + kk) * 64 + b4 * 4);
      }
    }
    __syncthreads();
#pragma unroll
    for (int kk = 0; kk < 64; ++kk) {
      float4 a = *(const float4*)(&Wt[kk * 68 + tr4 * 4]);
      float4 zb = *(const float4*)(&Zt[kk * 68 + tb4 * 4]);
      float av[4] = {a.x, a.y, a.z, a.w};
      float zv[4] = {zb.x, zb.y, zb.z, zb.w};
#pragma unroll
      for (int i = 0; i < 4; ++i)
#pragma unroll
        for (int j = 0; j < 4; ++j) acc[i][j] += av[i] * zv[j];
    }
    __syncthreads();
  }
#pragma unroll
  for (int i = 0; i < 4; ++i) {
    float4 o = make_float4(acc[i][0], acc[i][1], acc[i][2], acc[i][3]);
    *(float4*)(&part[((size_t)s * kFH + r0 + tr4 * 4 + i) * 64 + tb4 * 4]) = o;
  }
}

// ------------------------------------------------- lstm (+ hsplit fused) ----
__global__ __launch_bounds__(256) void lstm_kernel(
    const float* __restrict__ part, const float* __restrict__ bih,
    const float* __restrict__ bhh, float* __restrict__ h,
    float* __restrict__ c, unsigned short* __restrict__ Hhi,
    unsigned short* __restrict__ Hlo) {
  int g = blockIdx.x * 256 + threadIdx.x;
  int b = g & 63, u = g >> 6;
  float gate[4];
#pragma unroll
  for (int ty = 0; ty < 4; ++ty) {
    int r = ty * kH + u;
    float acc = bih[r] + bhh[r];
#pragma unroll
    for (int s2 = 0; s2 < 8; ++s2)
      acc += part[((size_t)s2 * kFH + r) * 64 + b];
    gate[ty] = acc;
  }
  float gi = 1.f / (1.f + expf(-gate[0]));
  float gf = 1.f / (1.f + expf(-gate[1]));
  float gg = tanhf(gate[2]);
  float go = 1.f / (1.f + expf(-gate[3]));
  float cn = gf * c[g] + gi * gg;
  float hn = go * tanhf(cn);
  c[g] = cn;
  h[g] = hn;
  unsigned short hb = f2bf(hn);
  Hhi[(size_t)b * kH + u] = hb;
  Hlo[(size_t)b * kH + u] = f2bf(hn - bf2f(hb));
}

// ------------------------------------------------------- logits (MFMA) ------
// out[b][v] = sum_k W[v][k] h[k][b] + bout[v]. Block 256 thr = 4 waves;
// wave = 32v x 64b; grid 250. Hhi/Hlo k-slice staged in LDS (XOR-granule
// swizzle: slot = c ^ (row&7) -> both stage-writes and frag reads are
// bank-balanced). W frags stay global, register double-buffered.
__global__ __launch_bounds__(256) void logits_mfma_kernel(
    const unsigned short* __restrict__ Whi, const unsigned short* __restrict__ Wlo,
    const unsigned short* __restrict__ Hhi, const unsigned short* __restrict__ Hlo,
    const float* __restrict__ bout, float* __restrict__ out,
    float* __restrict__ pmax_g, float* __restrict__ psum_g,
    int* __restrict__ pidx_g) {
  __shared__ __align__(16) unsigned short Hs[8192];  // [2][64 rows][8 granules]
  const int tid = threadIdx.x;
  const int wave = tid >> 6, lane = tid & 63;
  const int m = lane & 15, q = lane >> 4;
  const int v0 = blockIdx.x * 128 + wave * 32;
  const unsigned short* wp0 = Whi + (size_t)(v0 + m) * kH + q * 8;
  const unsigned short* wp1 = Whi + (size_t)(v0 + 16 + m) * kH + q * 8;
  const unsigned short* lp0 = Wlo + (size_t)(v0 + m) * kH + q * 8;
  const unsigned short* lp1 = Wlo + (size_t)(v0 + 16 + m) * kH + q * 8;

  // staging plan: 1024 granules (2 tiles x 64 rows x 8), 4 per thread
  const unsigned short* sptr[4];
  int sdst[4];
#pragma unroll
  for (int l = 0; l < 4; ++l) {
    int g = tid + 256 * l;
    int tile = g >> 9, row = (g >> 3) & 63, cg = g & 7;
    sptr[l] = (tile ? Hlo : Hhi) + (size_t)row * kH + cg * 8;
    sdst[l] = tile * 4096 + row * 64 + ((cg ^ (row & 7)) * 8);
  }

  f32x4 acc[2][4];
#pragma unroll
  for (int tv = 0; tv < 2; ++tv)
#pragma unroll
    for (int bt = 0; bt < 4; ++bt) acc[tv][bt] = (f32x4){0.f, 0.f, 0.f, 0.f};

  struct WF { bf16x8 ah[2], al[2]; };
  WF w0, w1;
  ush8 hreg[4];

  auto loadW = [&](WF& f, int ko) {
    f.ah[0] = *(const bf16x8*)(wp0 + ko);
    f.ah[1] = *(const bf16x8*)(wp1 + ko);
    f.al[0] = *(const bf16x8*)(lp0 + ko);
    f.al[1] = *(const bf16x8*)(lp1 + ko);
  };
  auto loadH = [&](int kc) {
#pragma unroll
    for (int l = 0; l < 4; ++l) hreg[l] = *(const ush8*)(sptr[l] + kc);
  };
  auto readHfrag = [&](bf16x8 bh[4], bf16x8 bl[4], int koff) {
    int gbase = q + (koff >> 3);  // q or q+4
#pragma unroll
    for (int bt = 0; bt < 4; ++bt) {
      int row = bt * 16 + m;
      int off = row * 64 + ((gbase ^ (row & 7)) * 8);
      bh[bt] = *(const bf16x8*)(Hs + off);
      bl[bt] = *(const bf16x8*)(Hs + 4096 + off);
    }
  };
  auto mfma3 = [&](const WF& f, bf16x8 bh[4], bf16x8 bl[4]) {
#pragma unroll
    for (int tv = 0; tv < 2; ++tv)
#pragma unroll
      for (int bt = 0; bt < 4; ++bt) {
        acc[tv][bt] = __builtin_amdgcn_mfma_f32_16x16x32_bf16(
            f.ah[tv], bh[bt], acc[tv][bt], 0, 0, 0);
        acc[tv][bt] = __builtin_amdgcn_mfma_f32_16x16x32_bf16(
            f.ah[tv], bl[bt], acc[tv][bt], 0, 0, 0);
        acc[tv][bt] = __builtin_amdgcn_mfma_f32_16x16x32_bf16(
            f.al[tv], bh[bt], acc[tv][bt], 0, 0, 0);
      }
  };

  loadH(0);
  loadW(w0, 0);
  for (int kc = 0; kc < kH; kc += 64) {
    __syncthreads();  // previous iteration's Hs reads complete
#pragma unroll
    for (int l = 0; l < 4; ++l) *(ush8*)(Hs + sdst[l]) = hreg[l];
    __syncthreads();
    if (kc + 64 < kH) loadH(kc + 64);  // prefetch next stage (T14)
    bf16x8 bh[4], bl[4];
    loadW(w1, kc + 32);
    readHfrag(bh, bl, 0);
    mfma3(w0, bh, bl);
    if (kc + 64 < kH) loadW(w0, kc + 64);
    readHfrag(bh, bl, 32);
    mfma3(w1, bh, bl);
  }

  // bias in-place; store logits. D layout: row(v)=q*4+reg, col(b)=lane&15.
  float4 bo0 = *(const float4*)(bout + v0 + q * 4);
  float4 bo1 = *(const float4*)(bout + v0 + 16 + q * 4);
#pragma unroll
  for (int tv = 0; tv < 2; ++tv) {
    float4 bo = tv ? bo1 : bo0;
#pragma unroll
    for (int bt = 0; bt < 4; ++bt) {
      int b = bt * 16 + m;
      f32x4 a = acc[tv][bt];
      a[0] += bo.x; a[1] += bo.y; a[2] += bo.z; a[3] += bo.w;
      acc[tv][bt] = a;
      float4 o = make_float4(a[0], a[1], a[2], a[3]);
      *(float4*)(out + (size_t)b * kV + v0 + tv * 16 + q * 4) = o;
    }
  }

  // ---- per-block softmax/argmax partials, layout [blk][64] (coalesced)
  __shared__ float lred[4][4][64];
  __shared__ int lidx[4][4][64];
  __shared__ float bbm[64];
  const int blk = blockIdx.x;
  const int vbase = blk * 128;

#pragma unroll
  for (int bt = 0; bt < 4; ++bt) {
    float pmv = -INFINITY;
    int piv = 0x7fffffff;
#pragma unroll
    for (int tv = 0; tv < 2; ++tv)
#pragma unroll
      for (int r = 0; r < 4; ++r) {
        float val = acc[tv][bt][r];
        int v = vbase + wave * 32 + tv * 16 + q * 4 + r;
        if (val > pmv) { pmv = val; piv = v; }  // strict >, v ascending
      }
    lred[wave][q][bt * 16 + m] = pmv;
    lidx[wave][q][bt * 16 + m] = piv;
  }
  __syncthreads();
  if (tid < 64) {
    float bm = -INFINITY;
    int bi = 0x7fffffff;
#pragma unroll
    for (int w = 0; w < 4; ++w)
#pragma unroll
      for (int qq = 0; qq < 4; ++qq) {
        float v2 = lred[w][qq][tid];
        int i2 = lidx[w][qq][tid];
        if (v2 > bm || (v2 == bm && i2 < bi)) { bm = v2; bi = i2; }
      }
    bbm[tid] = bm;
    pmax_g[(size_t)blk * 64 + tid] = bm;
    pidx_g[(size_t)blk * 64 + tid] = bi;
  }
  __syncthreads();
#pragma unroll
  for (int bt = 0; bt < 4; ++bt) {
    float bm = bbm[bt * 16 + m];
    float s = 0.f;
#pragma unroll
    for (int tv = 0; tv < 2; ++tv)
#pragma unroll
      for (int r = 0; r < 4; ++r) s += expf(acc[tv][bt][r] - bm);
    lred[wave][q][bt * 16 + m] = s;
  }
  __syncthreads();
  if (tid < 64) {
    float s = 0.f;
#pragma unroll
    for (int w = 0; w < 4; ++w)
#pragma unroll
      for (int qq = 0; qq < 4; ++qq) s += lred[w][qq][tid];
    psum_g[(size_t)blk * 64 + tid] = s;
  }
}

// --------------------------------------------- final mask (t = T-1 only) ----
__global__ __launch_bounds__(256) void final_mask_kernel(
    const float* __restrict__ pm, const float* __restrict__ ps,
    const float* __restrict__ out_t, float* __restrict__ mask) {
  __shared__ float rm[4][64];
  __shared__ float rs[4][64];
  const int tid = threadIdx.x;
  const int b = tid & 63, kq = tid >> 6;
  float mx = -INFINITY;
  for (int k = kq; k < 250; k += 4) {
    float v = pm[k * 64 + b];
    if (v > mx) mx = v;
  }
  rm[kq][b] = mx;
  __syncthreads();
  if (tid < 64) {
    float M = fmaxf(fmaxf(rm[0][tid], rm[1][tid]), fmaxf(rm[2][tid], rm[3][tid]));
    rm[0][tid] = M;
  }
  __syncthreads();
  float M = rm[0][b];
  float s = 0.f;
  for (int k = kq; k < 250; k += 4)
    s += ps[k * 64 + b] * expf(pm[k * 64 + b] - M);
  rs[kq][b] = s;
  __syncthreads();
  if (tid < 64) {
    float S = rs[0][tid] + rs[1][tid] + rs[2][tid] + rs[3][tid];
    mask[tid] = expf(out_t[(size_t)tid * kV + kEOS] - M) / S;
  }
}

// -------------------------------------------------------------- launch ------
extern "C" void kernel_launch(void* const* d_in, const int* in_sizes, int n_in,
                              void* d_out, int out_size, void* d_ws,
                              size_t ws_size, hipStream_t stream) {
  const float* E = (const float*)d_in[0];
  const float* Wih = (const float*)d_in[1];
  const float* Whh = (const float*)d_in[2];
  const float* bih = (const float*)d_in[3];
  const float* bhh = (const float*)d_in[4];
  const float* Wout = (const float*)d_in[5];
  const float* bout = (const float*)d_in[6];
  const float* eh = (const float*)d_in[7];
  const float* ec = (const float*)d_in[8];
  float* out = (float*)d_out;
  float* ws = (float*)d_ws;

  float* h = ws + 65536;
  float* c = ws + 131072;
  float* part = ws + 196608;  // reused R1 slot (8*4096*64 floats)
  float* pmaxg = ws + 2293760;
  float* psumg = ws + 2310144;
  int* pidxg = (int*)(ws + 2326528);
  unsigned short* Whi = (unsigned short*)(ws + 2359296);
  unsigned short* Wlo = Whi + (size_t)kV * kH;
  unsigned short* Hhi = Wlo + (size_t)kV * kH;
  unsigned short* Hlo = Hhi + (size_t)kB * kH;
  float* maskbase = out + (size_t)kT * kB * kV;

  init_kernel<<<512, 256, 0, stream>>>(eh, ec, ws);
  wsplit_kernel<<<kV, 256, 0, stream>>>(Wout, Whi, Wlo);
  for (int t = 0; t < kT; ++t) {
    float* out_t = out + (size_t)t * kB * kV;
    const float* out_prev = t ? out + (size_t)(t - 1) * kB * kV : nullptr;
    float* mask_prev = t ? maskbase + (size_t)(t - 1) * kB : nullptr;
    gates_kernel<<<dim3(64, 8), 256, 0, stream>>>(
        Wih, Whh, E, h, part, pmaxg, psumg, pidxg, out_prev, mask_prev, t);
    lstm_kernel<<<256, 256, 0, stream>>>(part, bih, bhh, h, c, Hhi, Hlo);
    logits_mfma_kernel<<<250, 256, 0, stream>>>(Whi, Wlo, Hhi, Hlo, bout,
                                                out_t, pmaxg, psumg, pidxg);
  }
  final_mask_kernel<<<1, 256, 0, stream>>>(
      pmaxg, psumg, out + (size_t)(kT - 1) * kB * kV,
      maskbase + (size_t)(kT - 1) * kB);
}